// Round 5
// baseline (48179.388 us; speedup 1.0000x reference)
//
#include <hip/hip_runtime.h>
#include <hip/hip_bf16.h>
#include <hip/hip_cooperative_groups.h>

namespace cg = cooperative_groups;

typedef _Float16 f16;
typedef f16  f16x8 __attribute__((ext_vector_type(8)));
typedef float f32x4 __attribute__((ext_vector_type(4)));

__device__ __forceinline__ f16x8 ld8h(const f16* p){ return *reinterpret_cast<const f16x8*>(p); }
__device__ __forceinline__ void fsplit(float x, f16* hi, f16* lo){
    f16 h=(f16)x; *hi=h; *lo=(f16)((x-(float)h)*4096.0f);
}
#define MFMA16(a,b,c) __builtin_amdgcn_mfma_f32_16x16x32_f16((a),(b),(c),0,0,0)
// fragment-major offset: 16(n)x32(k) fragment = 512 contiguous f16; within-frag = lane*8+e
__device__ __forceinline__ size_t fragoff(int n, int k, int Kc){
    return ((size_t)(n>>4)*Kc + (k>>5))*512 + (size_t)((((k&31)>>3)*16 + (n&15))*8 + (k&7));
}

// ---------------- element counts ----------------
constexpr size_t NXE   = 128ull*256*128;
constexpr size_t NPM   = 1024ull*4096;
constexpr size_t NWIH0 = 3072ull*384;
constexpr size_t NWIH12= 3072ull*256;
constexpr size_t NWIH3 = 3456ull*256;
constexpr size_t NWHH  = 3072ull*1024;
constexpr size_t NWHH3 = 3456ull*1152;
constexpr size_t NCEN  = 128ull*4096;
constexpr size_t NCTX  = 128ull*1024;
constexpr size_t NHMX  = 128ull*1152;

// ---------------- workspace offsets (bytes) ----------------
constexpr size_t OFF_XH    = 0;
constexpr size_t OFF_XL    = OFF_XH + NXE*2;
constexpr size_t OFF_PMH   = OFF_XL + NXE*2;
constexpr size_t OFF_PML   = OFF_PMH + NPM*2;
constexpr size_t OFF_WIHH0 = OFF_PML + NPM*2;
constexpr size_t OFF_WIHH1 = OFF_WIHH0 + NWIH0*2;
constexpr size_t OFF_WIHH2 = OFF_WIHH1 + NWIH12*2;
constexpr size_t OFF_WIHH3 = OFF_WIHH2 + NWIH12*2;
constexpr size_t OFF_WIHL0 = OFF_WIHH3 + NWIH3*2;
constexpr size_t OFF_WIHL1 = OFF_WIHL0 + NWIH0*2;
constexpr size_t OFF_WIHL2 = OFF_WIHL1 + NWIH12*2;
constexpr size_t OFF_WIHL3 = OFF_WIHL2 + NWIH12*2;
constexpr size_t OFF_WHHH0 = OFF_WIHL3 + NWIH3*2;
constexpr size_t OFF_WHHH1 = OFF_WHHH0 + NWHH*2;
constexpr size_t OFF_WHHH2 = OFF_WHHH1 + NWHH*2;
constexpr size_t OFF_WHHH3 = OFF_WHHH2 + NWHH*2;
constexpr size_t OFF_WHHL0 = OFF_WHHH3 + NWHH3*2;
constexpr size_t OFF_WHHL1 = OFF_WHHL0 + NWHH*2;
constexpr size_t OFF_WHHL2 = OFF_WHHL1 + NWHH*2;
constexpr size_t OFF_WHHL3 = OFF_WHHL2 + NWHH*2;
constexpr size_t OFF_CENH  = OFF_WHHL3 + NWHH3*2;   // [2 parities]
constexpr size_t OFF_CENL  = OFF_CENH + 2*NCEN*2;
constexpr size_t OFF_CTXH  = OFF_CENL + 2*NCEN*2;
constexpr size_t OFF_CTXL  = OFF_CTXH + NCTX*2;
constexpr size_t OFF_HH    = OFF_CTXL + NCTX*2;     // [(p*4+i)]
constexpr size_t OFF_HL    = OFF_HH + 8*NHMX*2;
constexpr size_t OFF_HF    = OFF_HL + 8*NHMX*2;     // fp32
constexpr size_t WS_NEED   = OFF_HF + 8*NHMX*4;     // ~116 MB

__device__ __forceinline__ f16* hh_ptr(char* ws,int p,int i){ return (f16*)(ws+OFF_HH+((size_t)(p*4+i))*NHMX*2); }
__device__ __forceinline__ f16* hl_ptr(char* ws,int p,int i){ return (f16*)(ws+OFF_HL+((size_t)(p*4+i))*NHMX*2); }
__device__ __forceinline__ float* hf_ptr(char* ws,int p,int i){ return (float*)(ws+OFF_HF+((size_t)(p*4+i))*NHMX*4); }

// ---------------- prep: repack to fragment-major ----------------
__global__ void k_repack_w(const float* __restrict__ src, f16* __restrict__ hi,
                           f16* __restrict__ lo, int K){
    int n = blockIdx.x;
    const float* row = src + (size_t)n*K;
    int Kc = K >> 5;
    for (int k8 = threadIdx.x*8; k8 < K; k8 += 2048) {
        f16x8 hv, lv;
        #pragma unroll
        for (int e = 0; e < 8; ++e) { f16 a,b; fsplit(row[k8+e], &a, &b); hv[e]=a; lv[e]=b; }
        size_t d = fragoff(n, k8, Kc);
        *reinterpret_cast<f16x8*>(hi + d) = hv;
        *reinterpret_cast<f16x8*>(lo + d) = lv;
    }
}

__global__ void k_repack_pm(const float* __restrict__ p0, const float* __restrict__ p1,
                            const float* __restrict__ p2, const float* __restrict__ p3,
                            f16* __restrict__ hi, f16* __restrict__ lo){
    int k0 = blockIdx.x * 8;
    for (int c = threadIdx.x; c < 1024; c += 256) {
        int i = c >> 8, nl = c & 255;
        const float* p = (i==0?p0 : i==1?p1 : i==2?p2 : p3);
        #pragma unroll
        for (int e = 0; e < 8; ++e) {
            f16 a,b; fsplit(p[(size_t)(k0+e)*256 + nl], &a, &b);
            size_t d = fragoff(c, k0+e, 128); hi[d]=a; lo[d]=b;
        }
    }
}

__global__ void k_repack_x(const float* __restrict__ src, f16* __restrict__ hi, f16* __restrict__ lo){
    size_t g = ((size_t)blockIdx.x*256 + threadIdx.x) * 8;
    if (g >= NXE) return;
    int m = (int)(g >> 15), t = (int)((g >> 7) & 255), d0 = (int)(g & 127);
    f16x8 hv, lv;
    #pragma unroll
    for (int e = 0; e < 8; ++e) { f16 a,b; fsplit(src[g+e], &a, &b); hv[e]=a; lv[e]=b; }
    size_t d = (size_t)t*16384 + fragoff(m, d0, 4);
    *reinterpret_cast<f16x8*>(hi + d) = hv;
    *reinterpret_cast<f16x8*>(lo + d) = lv;
}

__global__ void k_init_cen(const float* __restrict__ ci, char* ws){
    size_t g = ((size_t)blockIdx.x*256 + threadIdx.x) * 8;
    if (g >= 4ull*128*1024) return;
    int i = (int)(g >> 17), b = (int)((g >> 10) & 127), c = (int)(g & 1023);
    f16* hi = (f16*)(ws + OFF_CENH);
    f16* lo = (f16*)(ws + OFF_CENL);
    f16x8 hv, lv;
    #pragma unroll
    for (int e = 0; e < 8; ++e) { f16 a,bb; fsplit(ci[g+e], &a, &bb); hv[e]=a; lv[e]=bb; }
    size_t d = fragoff(b, i*1024 + c, 128);
    *reinterpret_cast<f16x8*>(hi + d) = hv;
    *reinterpret_cast<f16x8*>(lo + d) = lv;
}

__global__ void k_init_mod(const float* __restrict__ mi, char* ws){
    size_t g = ((size_t)blockIdx.x*256 + threadIdx.x) * 8;
    if (g >= 3ull*128*1024) return;
    int i = (int)(g >> 17), b = (int)((g >> 10) & 127), j = (int)(g & 1023);
    float* hf = hf_ptr(ws, 0, i);
    f16 *hh = hh_ptr(ws, 0, i), *hl = hl_ptr(ws, 0, i);
    f16x8 hv, lv;
    #pragma unroll
    for (int e = 0; e < 8; ++e) {
        float v = mi[g+e]; hf[(size_t)b*1024 + j + e] = v;
        f16 a,bb; fsplit(v, &a, &bb); hv[e]=a; lv[e]=bb;
    }
    size_t d = fragoff(b, j, 32);
    *reinterpret_cast<f16x8*>(hh + d) = hv;
    *reinterpret_cast<f16x8*>(hl + d) = lv;
}

__global__ void k_init_last(const float* __restrict__ ml, char* ws){
    int b = blockIdx.x;
    float* hf = hf_ptr(ws, 0, 3);
    f16 *hh = hh_ptr(ws, 0, 3), *hl = hl_ptr(ws, 0, 3);
    for (int j = threadIdx.x*8; j < 1152; j += 2048) {
        f16x8 hv, lv;
        #pragma unroll
        for (int e = 0; e < 8; ++e) {
            float v = ml[(size_t)b*1152 + j + e]; hf[(size_t)b*1152 + j + e] = v;
            f16 a,bb; fsplit(v, &a, &bb); hv[e]=a; lv[e]=bb;
        }
        size_t d = fragoff(b, j, 36);
        *reinterpret_cast<f16x8*>(hh + d) = hv;
        *reinterpret_cast<f16x8*>(hl + d) = lv;
    }
}

// ---------------- phase 2 work unit: 64 rows x 16 h-cols of one module ----------------
__device__ __forceinline__ void gates_unit(char* ws,
    const float* bih0, const float* bih1, const float* bih2, const float* bih3,
    const float* bhh0, const float* bhh1, const float* bhh2, const float* bhh3,
    float* out, int t, int par, int u, int lane, int wv)
{
    int tile = (u < 512) ? (u >> 1) : (256 + ((u - 512) >> 1));
    int half = u & 1;
    int i, jt;
    if (tile < 64)       { i = 0; jt = tile; }
    else if (tile < 128) { i = 1; jt = tile - 64; }
    else if (tile < 192) { i = 2; jt = tile - 128; }
    else                 { i = 3; jt = tile - 192; }
    const int H  = (i == 3) ? 1152 : 1024;
    const int K1 = (i == 0) ? 384 : 256;
    const int Kc1 = K1 >> 5, KcH = H >> 5, Ht = H >> 4;

    const f16* WihH = (const f16*)(ws + (i==0?OFF_WIHH0 : i==1?OFF_WIHH1 : i==2?OFF_WIHH2 : OFF_WIHH3));
    const f16* WihL = (const f16*)(ws + (i==0?OFF_WIHL0 : i==1?OFF_WIHL1 : i==2?OFF_WIHL2 : OFF_WIHL3));
    const f16* WhhH = (const f16*)(ws + (i==0?OFF_WHHH0 : i==1?OFF_WHHH1 : i==2?OFF_WHHH2 : OFF_WHHH3));
    const f16* WhhL = (const f16*)(ws + (i==0?OFF_WHHL0 : i==1?OFF_WHHL1 : i==2?OFF_WHHL2 : OFF_WHHL3));

    size_t lb = (size_t)lane*8;
    size_t b1[3], b2[3];
    #pragma unroll
    for (int s = 0; s < 3; ++s) {
        b1[s] = ((size_t)(s*Ht + jt)*Kc1)*512 + lb;
        b2[s] = ((size_t)(s*Ht + jt)*KcH)*512 + lb;
    }
    int mf = half*4 + wv;    // m-frag 0..7 (16 rows each)

    f32x4 rh={},rc={},zh={},zc={},inh={},inc={},nhh={},nhc={};

    // ---- ih GEMM: A = (i==0 ? [x_t | ctx0] : ctx_i) ----
    {
        const f16* XH_ = (const f16*)(ws + OFF_XH);
        const f16* XL_ = (const f16*)(ws + OFF_XL);
        const f16* CH_ = (const f16*)(ws + OFF_CTXH);
        const f16* CL_ = (const f16*)(ws + OFF_CTXL);
        size_t xb = ((size_t)(t*8 + mf)*4)*512 + lb;
        size_t cb = ((size_t)mf*32)*512 + lb;
        #pragma unroll 2
        for (int kc = 0; kc < Kc1; ++kc) {
            f16x8 ah, al;
            if (i == 0 && kc < 4) { ah = ld8h(XH_ + xb + kc*512); al = ld8h(XL_ + xb + kc*512); }
            else { int ck = (i == 0) ? kc - 4 : i*8 + kc;
                   ah = ld8h(CH_ + cb + ck*512); al = ld8h(CL_ + cb + ck*512); }
            f16x8 bh, bl;
            bh = ld8h(WihH + b1[0] + kc*512); bl = ld8h(WihL + b1[0] + kc*512);
            rh = MFMA16(ah,bh,rh); rc = MFMA16(al,bh,rc); rc = MFMA16(ah,bl,rc);
            bh = ld8h(WihH + b1[1] + kc*512); bl = ld8h(WihL + b1[1] + kc*512);
            zh = MFMA16(ah,bh,zh); zc = MFMA16(al,bh,zc); zc = MFMA16(ah,bl,zc);
            bh = ld8h(WihH + b1[2] + kc*512); bl = ld8h(WihL + b1[2] + kc*512);
            inh = MFMA16(ah,bh,inh); inc = MFMA16(al,bh,inc); inc = MFMA16(ah,bl,inc);
        }
    }
    // ---- hh GEMM: A = h_prev (parity par) ----
    {
        const f16* HHp = hh_ptr(ws, par, i);
        const f16* HLp = hl_ptr(ws, par, i);
        size_t hb = ((size_t)mf*KcH)*512 + lb;
        #pragma unroll 2
        for (int kc = 0; kc < KcH; ++kc) {
            f16x8 ah = ld8h(HHp + hb + kc*512), al = ld8h(HLp + hb + kc*512);
            f16x8 bh, bl;
            bh = ld8h(WhhH + b2[0] + kc*512); bl = ld8h(WhhL + b2[0] + kc*512);
            rh = MFMA16(ah,bh,rh); rc = MFMA16(al,bh,rc); rc = MFMA16(ah,bl,rc);
            bh = ld8h(WhhH + b2[1] + kc*512); bl = ld8h(WhhL + b2[1] + kc*512);
            zh = MFMA16(ah,bh,zh); zc = MFMA16(al,bh,zc); zc = MFMA16(ah,bl,zc);
            bh = ld8h(WhhH + b2[2] + kc*512); bl = ld8h(WhhL + b2[2] + kc*512);
            nhh = MFMA16(ah,bh,nhh); nhc = MFMA16(al,bh,nhc); nhc = MFMA16(ah,bl,nhc);
        }
    }
    // ---- GRU epilogue ----
    int rg = lane >> 4, fr = lane & 15;
    const float* bihp = (i==0?bih0 : i==1?bih1 : i==2?bih2 : bih3);
    const float* bhhp = (i==0?bhh0 : i==1?bhh1 : i==2?bhh2 : bhh3);
    int j = jt*16 + fr;
    float bir = bihp[j], biz = bihp[H+j], bin = bihp[2*H+j];
    float bhr = bhhp[j], bhz = bhhp[H+j], bhn = bhhp[2*H+j];
    const float* hfP = hf_ptr(ws, par, i);
    float* hfN = hf_ptr(ws, par^1, i);
    f16 *hhN = hh_ptr(ws, par^1, i), *hlN = hl_ptr(ws, par^1, i);
    f16* cenhN = (f16*)(ws + OFF_CENH) + (size_t)(par^1)*NCEN;
    f16* cenlN = (f16*)(ws + OFF_CENL) + (size_t)(par^1)*NCEN;
    const float inv = 1.0f/4096.0f;
    #pragma unroll
    for (int rr = 0; rr < 4; ++rr) {
        float r_  = rh[rr]  + rc[rr]*inv  + bir + bhr;
        float z_  = zh[rr]  + zc[rr]*inv  + biz + bhz;
        float in_ = inh[rr] + inc[rr]*inv + bin;
        float hn_ = nhh[rr] + nhc[rr]*inv + bhn;
        float rgt = 1.f/(1.f + expf(-r_));
        float zgt = 1.f/(1.f + expf(-z_));
        float ngt = tanhf(in_ + rgt*hn_);
        int m = half*64 + wv*16 + rg*4 + rr;
        float hp = hfP[(size_t)m*H + j];
        float hnew = (1.f - zgt)*ngt + zgt*hp;
        hfN[(size_t)m*H + j] = hnew;
        size_t hd = fragoff(m, j, KcH);
        fsplit(hnew, &hhN[hd], &hlN[hd]);
        if (i < 3) {
            size_t cd = fragoff(m, i*1024 + j, 128);
            fsplit(hnew, &cenhN[cd], &cenlN[cd]);
        } else if (j >= 128) {
            size_t cd = fragoff(m, 3072 + j - 128, 128);
            fsplit(hnew, &cenhN[cd], &cenlN[cd]);
        } else {
            out[((size_t)m*256 + t)*128 + j] = hnew;
        }
    }
}

// ---------------- persistent cooperative kernel: full 256-step scan ----------------
// grid 512 x 256 thr. Phase1: one 16x16 ctx tile/block (8x64). Phase2: 528 units.
__global__ __launch_bounds__(256, 2) void k_persist(char* ws,
    const float* __restrict__ bih0, const float* __restrict__ bih1,
    const float* __restrict__ bih2, const float* __restrict__ bih3,
    const float* __restrict__ bhh0, const float* __restrict__ bhh1,
    const float* __restrict__ bhh2, const float* __restrict__ bhh3,
    float* __restrict__ out)
{
    cg::grid_group grid = cg::this_grid();
    __shared__ float red[4][16][17];
    const int tid = threadIdx.x, lane = tid & 63, wv = tid >> 6;
    const int bid = blockIdx.x;
    const size_t lb = (size_t)lane*8;
    const f16* pmh = (const f16*)(ws + OFF_PMH);
    const f16* pml = (const f16*)(ws + OFF_PML);
    f16* ctxh = (f16*)(ws + OFF_CTXH);
    f16* ctxl = (f16*)(ws + OFF_CTXL);
    const int bm = bid >> 6, bn = bid & 63;

    for (int t = 0; t < 256; ++t) {
        const int par = t & 1;
        // ---------- phase 1: ctx = center @ pm (16x16 tile, 4-wave K-split) ----------
        {
            const f16* cenh = (const f16*)(ws + OFF_CENH) + (size_t)par*NCEN;
            const f16* cenl = (const f16*)(ws + OFF_CENL) + (size_t)par*NCEN;
            size_t ab = ((size_t)bm*128 + wv*32)*512 + lb;
            size_t bb = ((size_t)bn*128 + wv*32)*512 + lb;
            f32x4 h = {}, c = {};
            #pragma unroll 4
            for (int kc = 0; kc < 32; ++kc) {
                f16x8 ah = ld8h(cenh + ab + kc*512), al = ld8h(cenl + ab + kc*512);
                f16x8 bh = ld8h(pmh + bb + kc*512),  bl = ld8h(pml + bb + kc*512);
                h = MFMA16(ah,bh,h); c = MFMA16(al,bh,c); c = MFMA16(ah,bl,c);
            }
            int rg = lane >> 4, fr = lane & 15;
            const float inv = 1.0f/4096.0f;
            #pragma unroll
            for (int rr = 0; rr < 4; ++rr)
                red[wv][rg*4+rr][fr] = h[rr] + c[rr]*inv;
            __syncthreads();
            int r = tid >> 4, cc = tid & 15;
            float s = red[0][r][cc] + red[1][r][cc] + red[2][r][cc] + red[3][r][cc];
            size_t d = fragoff(bm*16 + r, bn*16 + cc, 32);
            fsplit(s, &ctxh[d], &ctxl[d]);
        }
        grid.sync();
        // ---------- phase 2: gates + GRU (528 units over 512 blocks) ----------
        gates_unit(ws, bih0,bih1,bih2,bih3, bhh0,bhh1,bhh2,bhh3, out, t, par, bid, lane, wv);
        if (bid < 16)
            gates_unit(ws, bih0,bih1,bih2,bih3, bhh0,bhh1,bhh2,bhh3, out, t, par, 512 + bid, lane, wv);
        grid.sync();
    }
}

// ---------------- host ----------------
extern "C" void kernel_launch(void* const* d_in, const int* in_sizes, int n_in,
                              void* d_out, int out_size, void* d_ws, size_t ws_size,
                              hipStream_t stream)
{
    char* ws = (char*)d_ws;
    const float* inp   = (const float*)d_in[0];
    const float* cini  = (const float*)d_in[1];
    const float* mini  = (const float*)d_in[2];
    const float* mlast = (const float*)d_in[3];
    const float *pm[4], *wih[4], *whh[4], *bih[4], *bhh[4];
    for (int i = 0; i < 4; ++i) {
        pm[i]  = (const float*)d_in[4 + 5*i];
        wih[i] = (const float*)d_in[5 + 5*i];
        whh[i] = (const float*)d_in[6 + 5*i];
        bih[i] = (const float*)d_in[7 + 5*i];
        bhh[i] = (const float*)d_in[8 + 5*i];
    }
    float* out = (float*)d_out;

    k_repack_x<<<2048, 256, 0, stream>>>(inp, (f16*)(ws+OFF_XH), (f16*)(ws+OFF_XL));
    k_repack_pm<<<512, 256, 0, stream>>>(pm[0], pm[1], pm[2], pm[3],
                                         (f16*)(ws+OFF_PMH), (f16*)(ws+OFF_PML));
    k_repack_w<<<3072, 256, 0, stream>>>(wih[0], (f16*)(ws+OFF_WIHH0), (f16*)(ws+OFF_WIHL0), 384);
    k_repack_w<<<3072, 256, 0, stream>>>(wih[1], (f16*)(ws+OFF_WIHH1), (f16*)(ws+OFF_WIHL1), 256);
    k_repack_w<<<3072, 256, 0, stream>>>(wih[2], (f16*)(ws+OFF_WIHH2), (f16*)(ws+OFF_WIHL2), 256);
    k_repack_w<<<3456, 256, 0, stream>>>(wih[3], (f16*)(ws+OFF_WIHH3), (f16*)(ws+OFF_WIHL3), 256);
    k_repack_w<<<3072, 256, 0, stream>>>(whh[0], (f16*)(ws+OFF_WHHH0), (f16*)(ws+OFF_WHHL0), 1024);
    k_repack_w<<<3072, 256, 0, stream>>>(whh[1], (f16*)(ws+OFF_WHHH1), (f16*)(ws+OFF_WHHL1), 1024);
    k_repack_w<<<3072, 256, 0, stream>>>(whh[2], (f16*)(ws+OFF_WHHH2), (f16*)(ws+OFF_WHHL2), 1024);
    k_repack_w<<<3456, 256, 0, stream>>>(whh[3], (f16*)(ws+OFF_WHHH3), (f16*)(ws+OFF_WHHL3), 1152);
    k_init_cen<<<256, 256, 0, stream>>>(cini, ws);
    k_init_mod<<<192, 256, 0, stream>>>(mini, ws);
    k_init_last<<<128, 256, 0, stream>>>(mlast, ws);

    char* wsp = ws;
    const float *b0 = bih[0], *b1 = bih[1], *b2 = bih[2], *b3 = bih[3];
    const float *h0 = bhh[0], *h1 = bhh[1], *h2 = bhh[2], *h3 = bhh[3];
    float* outp = out;
    void* args[] = { &wsp, &b0, &b1, &b2, &b3, &h0, &h1, &h2, &h3, &outp };
    hipLaunchCooperativeKernel(reinterpret_cast<void*>(k_persist),
                               dim3(512), dim3(256), args, 0, stream);
    (void)in_sizes; (void)n_in; (void)out_size; (void)ws_size; (void)WS_NEED;
}

// Round 6
// 24328.610 us; speedup vs baseline: 1.9804x; 1.9804x over previous
//
#include <hip/hip_runtime.h>
#include <hip/hip_bf16.h>

typedef _Float16 f16;
typedef f16  f16x8 __attribute__((ext_vector_type(8)));
typedef float f32x4 __attribute__((ext_vector_type(4)));

__device__ __forceinline__ f16x8 ld8h(const f16* p){ return *reinterpret_cast<const f16x8*>(p); }
__device__ __forceinline__ void fsplit(float x, f16* hi, f16* lo){
    f16 h=(f16)x; *hi=h; *lo=(f16)((x-(float)h)*4096.0f);
}
#define MFMA16(a,b,c) __builtin_amdgcn_mfma_f32_16x16x32_f16((a),(b),(c),0,0,0)
// fragment-major offset: 16(n)x32(k) fragment = 512 contiguous f16; within-frag = lane*8+e
__device__ __forceinline__ size_t fragoff(int n, int k, int Kc){
    return ((size_t)(n>>4)*Kc + (k>>5))*512 + (size_t)((((k&31)>>3)*16 + (n&15))*8 + (k&7));
}
// async global->LDS, 16B per lane; LDS dest wave-uniform (HW adds lane*16)
__device__ __forceinline__ void gl_lds16(const f16* g, f16* l){
    __builtin_amdgcn_global_load_lds(
        (const __attribute__((address_space(1))) void*)g,
        (__attribute__((address_space(3))) void*)l, 16, 0, 0);
}

// ---------------- element counts ----------------
constexpr size_t NXE   = 128ull*256*128;
constexpr size_t NPM   = 1024ull*4096;
constexpr size_t NWIH0 = 3072ull*384;
constexpr size_t NWIH12= 3072ull*256;
constexpr size_t NWIH3 = 3456ull*256;
constexpr size_t NWHH  = 3072ull*1024;
constexpr size_t NWHH3 = 3456ull*1152;
constexpr size_t NCEN  = 128ull*4096;
constexpr size_t NCTX  = 128ull*1024;
constexpr size_t NHMX  = 128ull*1152;

// ---------------- workspace offsets (bytes) ----------------
constexpr size_t OFF_XH    = 0;
constexpr size_t OFF_XL    = OFF_XH + NXE*2;
constexpr size_t OFF_PMH   = OFF_XL + NXE*2;
constexpr size_t OFF_PML   = OFF_PMH + NPM*2;
constexpr size_t OFF_WIHH0 = OFF_PML + NPM*2;
constexpr size_t OFF_WIHH1 = OFF_WIHH0 + NWIH0*2;
constexpr size_t OFF_WIHH2 = OFF_WIHH1 + NWIH12*2;
constexpr size_t OFF_WIHH3 = OFF_WIHH2 + NWIH12*2;
constexpr size_t OFF_WIHL0 = OFF_WIHH3 + NWIH3*2;
constexpr size_t OFF_WIHL1 = OFF_WIHL0 + NWIH0*2;
constexpr size_t OFF_WIHL2 = OFF_WIHL1 + NWIH12*2;
constexpr size_t OFF_WIHL3 = OFF_WIHL2 + NWIH12*2;
constexpr size_t OFF_WHHH0 = OFF_WIHL3 + NWIH3*2;
constexpr size_t OFF_WHHH1 = OFF_WHHH0 + NWHH*2;
constexpr size_t OFF_WHHH2 = OFF_WHHH1 + NWHH*2;
constexpr size_t OFF_WHHH3 = OFF_WHHH2 + NWHH*2;
constexpr size_t OFF_WHHL0 = OFF_WHHH3 + NWHH3*2;
constexpr size_t OFF_WHHL1 = OFF_WHHL0 + NWHH*2;
constexpr size_t OFF_WHHL2 = OFF_WHHL1 + NWHH*2;
constexpr size_t OFF_WHHL3 = OFF_WHHL2 + NWHH*2;
constexpr size_t OFF_CENH  = OFF_WHHL3 + NWHH3*2;   // [2 parities]
constexpr size_t OFF_CENL  = OFF_CENH + 2*NCEN*2;
constexpr size_t OFF_CTXH  = OFF_CENL + 2*NCEN*2;
constexpr size_t OFF_CTXL  = OFF_CTXH + NCTX*2;
constexpr size_t OFF_HH    = OFF_CTXL + NCTX*2;     // [(p*4+i)]
constexpr size_t OFF_HL    = OFF_HH + 8*NHMX*2;
constexpr size_t OFF_HF    = OFF_HL + 8*NHMX*2;     // fp32
constexpr size_t WS_NEED   = OFF_HF + 8*NHMX*4;     // ~116 MB

__device__ __forceinline__ f16* hh_ptr(char* ws,int p,int i){ return (f16*)(ws+OFF_HH+((size_t)(p*4+i))*NHMX*2); }
__device__ __forceinline__ f16* hl_ptr(char* ws,int p,int i){ return (f16*)(ws+OFF_HL+((size_t)(p*4+i))*NHMX*2); }
__device__ __forceinline__ float* hf_ptr(char* ws,int p,int i){ return (float*)(ws+OFF_HF+((size_t)(p*4+i))*NHMX*4); }

// ---------------- prep: repack to fragment-major ----------------
__global__ void k_repack_w(const float* __restrict__ src, f16* __restrict__ hi,
                           f16* __restrict__ lo, int K){
    int n = blockIdx.x;
    const float* row = src + (size_t)n*K;
    int Kc = K >> 5;
    for (int k8 = threadIdx.x*8; k8 < K; k8 += 2048) {
        f16x8 hv, lv;
        #pragma unroll
        for (int e = 0; e < 8; ++e) { f16 a,b; fsplit(row[k8+e], &a, &b); hv[e]=a; lv[e]=b; }
        size_t d = fragoff(n, k8, Kc);
        *reinterpret_cast<f16x8*>(hi + d) = hv;
        *reinterpret_cast<f16x8*>(lo + d) = lv;
    }
}

__global__ void k_repack_pm(const float* __restrict__ p0, const float* __restrict__ p1,
                            const float* __restrict__ p2, const float* __restrict__ p3,
                            f16* __restrict__ hi, f16* __restrict__ lo){
    int k0 = blockIdx.x * 8;
    for (int c = threadIdx.x; c < 1024; c += 256) {
        int i = c >> 8, nl = c & 255;
        const float* p = (i==0?p0 : i==1?p1 : i==2?p2 : p3);
        #pragma unroll
        for (int e = 0; e < 8; ++e) {
            f16 a,b; fsplit(p[(size_t)(k0+e)*256 + nl], &a, &b);
            size_t d = fragoff(c, k0+e, 128); hi[d]=a; lo[d]=b;
        }
    }
}

__global__ void k_repack_x(const float* __restrict__ src, f16* __restrict__ hi, f16* __restrict__ lo){
    size_t g = ((size_t)blockIdx.x*256 + threadIdx.x) * 8;
    if (g >= NXE) return;
    int m = (int)(g >> 15), t = (int)((g >> 7) & 255), d0 = (int)(g & 127);
    f16x8 hv, lv;
    #pragma unroll
    for (int e = 0; e < 8; ++e) { f16 a,b; fsplit(src[g+e], &a, &b); hv[e]=a; lv[e]=b; }
    size_t d = (size_t)t*16384 + fragoff(m, d0, 4);
    *reinterpret_cast<f16x8*>(hi + d) = hv;
    *reinterpret_cast<f16x8*>(lo + d) = lv;
}

__global__ void k_init_cen(const float* __restrict__ ci, char* ws){
    size_t g = ((size_t)blockIdx.x*256 + threadIdx.x) * 8;
    if (g >= 4ull*128*1024) return;
    int i = (int)(g >> 17), b = (int)((g >> 10) & 127), c = (int)(g & 1023);
    f16* hi = (f16*)(ws + OFF_CENH);
    f16* lo = (f16*)(ws + OFF_CENL);
    f16x8 hv, lv;
    #pragma unroll
    for (int e = 0; e < 8; ++e) { f16 a,bb; fsplit(ci[g+e], &a, &bb); hv[e]=a; lv[e]=bb; }
    size_t d = fragoff(b, i*1024 + c, 128);
    *reinterpret_cast<f16x8*>(hi + d) = hv;
    *reinterpret_cast<f16x8*>(lo + d) = lv;
}

__global__ void k_init_mod(const float* __restrict__ mi, char* ws){
    size_t g = ((size_t)blockIdx.x*256 + threadIdx.x) * 8;
    if (g >= 3ull*128*1024) return;
    int i = (int)(g >> 17), b = (int)((g >> 10) & 127), j = (int)(g & 1023);
    float* hf = hf_ptr(ws, 0, i);
    f16 *hh = hh_ptr(ws, 0, i), *hl = hl_ptr(ws, 0, i);
    f16x8 hv, lv;
    #pragma unroll
    for (int e = 0; e < 8; ++e) {
        float v = mi[g+e]; hf[(size_t)b*1024 + j + e] = v;
        f16 a,bb; fsplit(v, &a, &bb); hv[e]=a; lv[e]=bb;
    }
    size_t d = fragoff(b, j, 32);
    *reinterpret_cast<f16x8*>(hh + d) = hv;
    *reinterpret_cast<f16x8*>(hl + d) = lv;
}

__global__ void k_init_last(const float* __restrict__ ml, char* ws){
    int b = blockIdx.x;
    float* hf = hf_ptr(ws, 0, 3);
    f16 *hh = hh_ptr(ws, 0, 3), *hl = hl_ptr(ws, 0, 3);
    for (int j = threadIdx.x*8; j < 1152; j += 2048) {
        f16x8 hv, lv;
        #pragma unroll
        for (int e = 0; e < 8; ++e) {
            float v = ml[(size_t)b*1152 + j + e]; hf[(size_t)b*1152 + j + e] = v;
            f16 a,bb; fsplit(v, &a, &bb); hv[e]=a; lv[e]=bb;
        }
        size_t d = fragoff(b, j, 36);
        *reinterpret_cast<f16x8*>(hh + d) = hv;
        *reinterpret_cast<f16x8*>(hl + d) = lv;
    }
}

// ---------------- step kernel 1: ctx = center @ pm (R4 version, unchanged) ----------------
// 256 blocks x 512 thr: tile (32 rows x 16 cols), 8-wave K-split (512 each), LDS reduce.
__global__ __launch_bounds__(512) void k_ctx(char* ws, int par){
    __shared__ float red[8][32][17];
    const f16* cenh = (const f16*)(ws + OFF_CENH) + (size_t)par*NCEN;
    const f16* cenl = (const f16*)(ws + OFF_CENL) + (size_t)par*NCEN;
    const f16* pmh  = (const f16*)(ws + OFF_PMH);
    const f16* pml  = (const f16*)(ws + OFF_PML);
    int tid = threadIdx.x, lane = tid & 63, wv = tid >> 6;
    int bm = blockIdx.x >> 6, bn = blockIdx.x & 63;
    size_t lb = (size_t)lane*8;
    size_t a0 = ((size_t)(bm*2)*128 + wv*16)*512 + lb;
    size_t a1 = a0 + 128*512;
    size_t bb = ((size_t)bn*128 + wv*16)*512 + lb;
    f32x4 h0={},h1={},c0={},c1={};
    #pragma unroll 4
    for (int kc = 0; kc < 16; ++kc) {
        f16x8 bh = ld8h(pmh + bb + kc*512), bl = ld8h(pml + bb + kc*512);
        f16x8 ah0 = ld8h(cenh + a0 + kc*512), al0 = ld8h(cenl + a0 + kc*512);
        f16x8 ah1 = ld8h(cenh + a1 + kc*512), al1 = ld8h(cenl + a1 + kc*512);
        h0 = MFMA16(ah0,bh,h0); c0 = MFMA16(al0,bh,c0); c0 = MFMA16(ah0,bl,c0);
        h1 = MFMA16(ah1,bh,h1); c1 = MFMA16(al1,bh,c1); c1 = MFMA16(ah1,bl,c1);
    }
    int rg = lane >> 4, fr = lane & 15;
    const float inv = 1.0f/4096.0f;
    #pragma unroll
    for (int rr = 0; rr < 4; ++rr) {
        red[wv][rg*4+rr][fr]      = h0[rr] + c0[rr]*inv;
        red[wv][16+rg*4+rr][fr]   = h1[rr] + c1[rr]*inv;
    }
    __syncthreads();
    int r = tid >> 4, c = tid & 15;   // 512 threads = 32x16
    float s = red[0][r][c]+red[1][r][c]+red[2][r][c]+red[3][r][c]
            + red[4][r][c]+red[5][r][c]+red[6][r][c]+red[7][r][c];
    int m = bm*32 + r, n = bn*16 + c;
    size_t d = fragoff(m, n, 32);
    f16* ctxh = (f16*)(ws + OFF_CTXH);
    f16* ctxl = (f16*)(ws + OFF_CTXL);
    fsplit(s, &ctxh[d], &ctxl[d]);
}

// ---------------- step kernel 2: fused gates+GRU, B staged via LDS dbuf (2-phase) ----------------
// 264 blocks x 256 thr: block = (module i, 16 h-cols) x 128 rows; wave = 2 m-frags.
__global__ __launch_bounds__(256, 2) void k_fused(char* ws,
    const float* __restrict__ bih0, const float* __restrict__ bih1,
    const float* __restrict__ bih2, const float* __restrict__ bih3,
    const float* __restrict__ bhh0, const float* __restrict__ bhh1,
    const float* __restrict__ bhh2, const float* __restrict__ bhh3,
    float* __restrict__ out, int t, int par)
{
    __shared__ f16 Bs[2][3][2][1024];   // [buf][gate][hi/lo][2kc x 512]
    const int tid = threadIdx.x, lane = tid & 63, wv = tid >> 6;
    const int fr = lane & 15, rg = lane >> 4;
    const int tile = blockIdx.x;
    int i, jt;
    if (tile < 64)       { i = 0; jt = tile; }
    else if (tile < 128) { i = 1; jt = tile - 64; }
    else if (tile < 192) { i = 2; jt = tile - 128; }
    else                 { i = 3; jt = tile - 192; }
    const int H  = (i == 3) ? 1152 : 1024;
    const int K1 = (i == 0) ? 384 : 256;
    const int Kc1 = K1 >> 5, KcH = H >> 5, Ht = H >> 4;
    const int P1 = Kc1 >> 1, P = P1 + (KcH >> 1);

    const f16* WihH = (const f16*)(ws + (i==0?OFF_WIHH0 : i==1?OFF_WIHH1 : i==2?OFF_WIHH2 : OFF_WIHH3));
    const f16* WihL = (const f16*)(ws + (i==0?OFF_WIHL0 : i==1?OFF_WIHL1 : i==2?OFF_WIHL2 : OFF_WIHL3));
    const f16* WhhH = (const f16*)(ws + (i==0?OFF_WHHH0 : i==1?OFF_WHHH1 : i==2?OFF_WHHH2 : OFF_WHHH3));
    const f16* WhhL = (const f16*)(ws + (i==0?OFF_WHHL0 : i==1?OFF_WHHL1 : i==2?OFF_WHHL2 : OFF_WHHL3));
    size_t b1[3], b2[3];
    #pragma unroll
    for (int s = 0; s < 3; ++s) {
        b1[s] = ((size_t)(s*Ht + jt)*Kc1)*512;
        b2[s] = ((size_t)(s*Ht + jt)*KcH)*512;
    }
    const size_t lb = (size_t)lane*8;
    const int mt0 = wv*2;
    const f16* XH_ = (const f16*)(ws + OFF_XH);
    const f16* XL_ = (const f16*)(ws + OFF_XL);
    const f16* CH_ = (const f16*)(ws + OFF_CTXH);
    const f16* CL_ = (const f16*)(ws + OFF_CTXL);
    const f16* HHp = hh_ptr(ws, par, i);
    const f16* HLp = hl_ptr(ws, par, i);
    const size_t xb0 = ((size_t)(t*8 + mt0)*4)*512 + lb, xb1 = xb0 + 2048;
    const size_t cb0 = ((size_t)mt0*32)*512 + lb,        cb1 = cb0 + 16384;
    const size_t hb0 = ((size_t)mt0*KcH)*512 + lb,       hb1 = hb0 + (size_t)KcH*512;

    f32x4 rh[2]={{},{}}, rc[2]={{},{}}, zh[2]={{},{}}, zc[2]={{},{}};
    f32x4 inh[2]={{},{}}, inc[2]={{},{}}, nhh[2]={{},{}}, nhc[2]={{},{}};

    // stage pair p into Bs[p&1]: 12 x 1KB sub-chunks, 3 per wave
    auto stage = [&](int p){
        const int buf = p & 1;
        const bool ih = p < P1;
        const int lp = ih ? p : p - P1;
        #pragma unroll
        for (int q = 0; q < 3; ++q) {
            const int c = wv*3 + q;
            const int s = c >> 2, a = (c >> 1) & 1, hlf = c & 1;
            const f16* base = ih ? (a ? WihL : WihH) : (a ? WhhL : WhhH);
            const size_t off = (ih ? b1[s] : b2[s]) + (size_t)lp*1024 + (size_t)hlf*512 + lb;
            gl_lds16(base + off, &Bs[buf][s][a][hlf*512]);
        }
    };

    auto compute = [&](int p){
        const int buf = p & 1;
        const bool ih = p < P1;
        const int lp = ih ? p : p - P1;
        #pragma unroll
        for (int kl = 0; kl < 2; ++kl) {
            const int kc = lp*2 + kl;
            f16x8 ah0, al0, ah1, al1;
            if (ih) {
                if (i == 0 && kc < 4) {
                    ah0 = ld8h(XH_ + xb0 + kc*512); al0 = ld8h(XL_ + xb0 + kc*512);
                    ah1 = ld8h(XH_ + xb1 + kc*512); al1 = ld8h(XL_ + xb1 + kc*512);
                } else {
                    const int ck = (i == 0) ? kc - 4 : i*8 + kc;
                    ah0 = ld8h(CH_ + cb0 + ck*512); al0 = ld8h(CL_ + cb0 + ck*512);
                    ah1 = ld8h(CH_ + cb1 + ck*512); al1 = ld8h(CL_ + cb1 + ck*512);
                }
            } else {
                ah0 = ld8h(HHp + hb0 + kc*512); al0 = ld8h(HLp + hb0 + kc*512);
                ah1 = ld8h(HHp + hb1 + kc*512); al1 = ld8h(HLp + hb1 + kc*512);
            }
            const f16* bsl = &Bs[buf][0][0][kl*512 + lane*8];
            f16x8 bh, bl;
            // gate r (s=0)
            bh = *(const f16x8*)(bsl);          bl = *(const f16x8*)(bsl + 1024);
            rh[0]=MFMA16(ah0,bh,rh[0]); rc[0]=MFMA16(al0,bh,rc[0]); rc[0]=MFMA16(ah0,bl,rc[0]);
            rh[1]=MFMA16(ah1,bh,rh[1]); rc[1]=MFMA16(al1,bh,rc[1]); rc[1]=MFMA16(ah1,bl,rc[1]);
            // gate z (s=1)
            bh = *(const f16x8*)(bsl + 2048);   bl = *(const f16x8*)(bsl + 3072);
            zh[0]=MFMA16(ah0,bh,zh[0]); zc[0]=MFMA16(al0,bh,zc[0]); zc[0]=MFMA16(ah0,bl,zc[0]);
            zh[1]=MFMA16(ah1,bh,zh[1]); zc[1]=MFMA16(al1,bh,zc[1]); zc[1]=MFMA16(ah1,bl,zc[1]);
            // gate n (s=2): ih -> in, hh -> hn
            bh = *(const f16x8*)(bsl + 4096);   bl = *(const f16x8*)(bsl + 5120);
            if (ih) {
                inh[0]=MFMA16(ah0,bh,inh[0]); inc[0]=MFMA16(al0,bh,inc[0]); inc[0]=MFMA16(ah0,bl,inc[0]);
                inh[1]=MFMA16(ah1,bh,inh[1]); inc[1]=MFMA16(al1,bh,inc[1]); inc[1]=MFMA16(ah1,bl,inc[1]);
            } else {
                nhh[0]=MFMA16(ah0,bh,nhh[0]); nhc[0]=MFMA16(al0,bh,nhc[0]); nhc[0]=MFMA16(ah0,bl,nhc[0]);
                nhh[1]=MFMA16(ah1,bh,nhh[1]); nhc[1]=MFMA16(al1,bh,nhc[1]); nhc[1]=MFMA16(ah1,bl,nhc[1]);
            }
        }
    };

    stage(0);
    __syncthreads();                       // drains vmcnt(0): buf0 ready
    for (int p = 0; p < P; ++p) {
        if (p + 1 < P) stage(p + 1);       // issue next tile (async, overlaps compute)
        compute(p);
        __syncthreads();                   // drain staged loads + all reads of buf[p&1]
    }

    // ---- GRU epilogue ----
    const float* bihp = (i==0?bih0 : i==1?bih1 : i==2?bih2 : bih3);
    const float* bhhp = (i==0?bhh0 : i==1?bhh1 : i==2?bhh2 : bhh3);
    const int j = jt*16 + fr;
    const float bir = bihp[j], biz = bihp[H+j], bin = bihp[2*H+j];
    const float bhr = bhhp[j], bhz = bhhp[H+j], bhn = bhhp[2*H+j];
    const float* hfP = hf_ptr(ws, par, i);
    float* hfN = hf_ptr(ws, par^1, i);
    f16 *hhN = hh_ptr(ws, par^1, i), *hlN = hl_ptr(ws, par^1, i);
    f16* cenhN = (f16*)(ws + OFF_CENH) + (size_t)(par^1)*NCEN;
    f16* cenlN = (f16*)(ws + OFF_CENL) + (size_t)(par^1)*NCEN;
    const float inv = 1.0f/4096.0f;
    #pragma unroll
    for (int mf = 0; mf < 2; ++mf) {
        #pragma unroll
        for (int rr = 0; rr < 4; ++rr) {
            float r_  = rh[mf][rr]  + rc[mf][rr]*inv  + bir + bhr;
            float z_  = zh[mf][rr]  + zc[mf][rr]*inv  + biz + bhz;
            float in_ = inh[mf][rr] + inc[mf][rr]*inv + bin;
            float hn_ = nhh[mf][rr] + nhc[mf][rr]*inv + bhn;
            float rgt = 1.f/(1.f + expf(-r_));
            float zgt = 1.f/(1.f + expf(-z_));
            float ngt = tanhf(in_ + rgt*hn_);
            int m = wv*32 + mf*16 + rg*4 + rr;
            float hp = hfP[(size_t)m*H + j];
            float hnew = (1.f - zgt)*ngt + zgt*hp;
            hfN[(size_t)m*H + j] = hnew;
            size_t hd = fragoff(m, j, KcH);
            fsplit(hnew, &hhN[hd], &hlN[hd]);
            if (i < 3) {
                size_t cd = fragoff(m, i*1024 + j, 128);
                fsplit(hnew, &cenhN[cd], &cenlN[cd]);
            } else if (j >= 128) {
                size_t cd = fragoff(m, 3072 + j - 128, 128);
                fsplit(hnew, &cenhN[cd], &cenlN[cd]);
            } else {
                out[((size_t)m*256 + t)*128 + j] = hnew;
            }
        }
    }
}

// ---------------- host ----------------
extern "C" void kernel_launch(void* const* d_in, const int* in_sizes, int n_in,
                              void* d_out, int out_size, void* d_ws, size_t ws_size,
                              hipStream_t stream)
{
    char* ws = (char*)d_ws;
    const float* inp   = (const float*)d_in[0];
    const float* cini  = (const float*)d_in[1];
    const float* mini  = (const float*)d_in[2];
    const float* mlast = (const float*)d_in[3];
    const float *pm[4], *wih[4], *whh[4], *bih[4], *bhh[4];
    for (int i = 0; i < 4; ++i) {
        pm[i]  = (const float*)d_in[4 + 5*i];
        wih[i] = (const float*)d_in[5 + 5*i];
        whh[i] = (const float*)d_in[6 + 5*i];
        bih[i] = (const float*)d_in[7 + 5*i];
        bhh[i] = (const float*)d_in[8 + 5*i];
    }
    float* out = (float*)d_out;

    k_repack_x<<<2048, 256, 0, stream>>>(inp, (f16*)(ws+OFF_XH), (f16*)(ws+OFF_XL));
    k_repack_pm<<<512, 256, 0, stream>>>(pm[0], pm[1], pm[2], pm[3],
                                         (f16*)(ws+OFF_PMH), (f16*)(ws+OFF_PML));
    k_repack_w<<<3072, 256, 0, stream>>>(wih[0], (f16*)(ws+OFF_WIHH0), (f16*)(ws+OFF_WIHL0), 384);
    k_repack_w<<<3072, 256, 0, stream>>>(wih[1], (f16*)(ws+OFF_WIHH1), (f16*)(ws+OFF_WIHL1), 256);
    k_repack_w<<<3072, 256, 0, stream>>>(wih[2], (f16*)(ws+OFF_WIHH2), (f16*)(ws+OFF_WIHL2), 256);
    k_repack_w<<<3456, 256, 0, stream>>>(wih[3], (f16*)(ws+OFF_WIHH3), (f16*)(ws+OFF_WIHL3), 256);
    k_repack_w<<<3072, 256, 0, stream>>>(whh[0], (f16*)(ws+OFF_WHHH0), (f16*)(ws+OFF_WHHL0), 1024);
    k_repack_w<<<3072, 256, 0, stream>>>(whh[1], (f16*)(ws+OFF_WHHH1), (f16*)(ws+OFF_WHHL1), 1024);
    k_repack_w<<<3072, 256, 0, stream>>>(whh[2], (f16*)(ws+OFF_WHHH2), (f16*)(ws+OFF_WHHL2), 1024);
    k_repack_w<<<3456, 256, 0, stream>>>(whh[3], (f16*)(ws+OFF_WHHH3), (f16*)(ws+OFF_WHHL3), 1152);
    k_init_cen<<<256, 256, 0, stream>>>(cini, ws);
    k_init_mod<<<192, 256, 0, stream>>>(mini, ws);
    k_init_last<<<128, 256, 0, stream>>>(mlast, ws);

    for (int t = 0; t < 256; ++t) {
        int par = t & 1;
        k_ctx<<<256, 512, 0, stream>>>(ws, par);
        k_fused<<<264, 256, 0, stream>>>(ws,
            bih[0], bih[1], bih[2], bih[3],
            bhh[0], bhh[1], bhh[2], bhh[3],
            out, t, par);
    }
    (void)in_sizes; (void)n_in; (void)out_size; (void)ws_size; (void)WS_NEED;
}

// Round 7
// 18685.211 us; speedup vs baseline: 2.5785x; 1.3020x over previous
//
#include <hip/hip_runtime.h>
#include <hip/hip_bf16.h>

typedef _Float16 f16;
typedef f16  f16x8 __attribute__((ext_vector_type(8)));
typedef float f32x4 __attribute__((ext_vector_type(4)));

__device__ __forceinline__ f16x8 ld8h(const f16* p){ return *reinterpret_cast<const f16x8*>(p); }
__device__ __forceinline__ void fsplit(float x, f16* hi, f16* lo){
    f16 h=(f16)x; *hi=h; *lo=(f16)((x-(float)h)*4096.0f);
}
#define MFMA16(a,b,c) __builtin_amdgcn_mfma_f32_16x16x32_f16((a),(b),(c),0,0,0)
// fragment-major offset: 16(n)x32(k) fragment = 512 contiguous f16; within-frag = lane*8+e
__device__ __forceinline__ size_t fragoff(int n, int k, int Kc){
    return ((size_t)(n>>4)*Kc + (k>>5))*512 + (size_t)((((k&31)>>3)*16 + (n&15))*8 + (k&7));
}

// ---------------- element counts ----------------
constexpr size_t NXE   = 128ull*256*128;
constexpr size_t NPM   = 1024ull*4096;
constexpr size_t NWIH0 = 3072ull*384;
constexpr size_t NWIH12= 3072ull*256;
constexpr size_t NWIH3 = 3456ull*256;
constexpr size_t NWHH  = 3072ull*1024;
constexpr size_t NWHH3 = 3456ull*1152;
constexpr size_t NCEN  = 128ull*4096;
constexpr size_t NCTX  = 128ull*1024;
constexpr size_t NHMX  = 128ull*1152;

// ---------------- workspace offsets (bytes) ----------------
constexpr size_t OFF_XH    = 0;
constexpr size_t OFF_XL    = OFF_XH + NXE*2;
constexpr size_t OFF_PMH   = OFF_XL + NXE*2;
constexpr size_t OFF_PML   = OFF_PMH + NPM*2;
constexpr size_t OFF_WIHH0 = OFF_PML + NPM*2;
constexpr size_t OFF_WIHH1 = OFF_WIHH0 + NWIH0*2;
constexpr size_t OFF_WIHH2 = OFF_WIHH1 + NWIH12*2;
constexpr size_t OFF_WIHH3 = OFF_WIHH2 + NWIH12*2;
constexpr size_t OFF_WIHL0 = OFF_WIHH3 + NWIH3*2;
constexpr size_t OFF_WIHL1 = OFF_WIHL0 + NWIH0*2;
constexpr size_t OFF_WIHL2 = OFF_WIHL1 + NWIH12*2;
constexpr size_t OFF_WIHL3 = OFF_WIHL2 + NWIH12*2;
constexpr size_t OFF_WHHH0 = OFF_WIHL3 + NWIH3*2;
constexpr size_t OFF_WHHH1 = OFF_WHHH0 + NWHH*2;
constexpr size_t OFF_WHHH2 = OFF_WHHH1 + NWHH*2;
constexpr size_t OFF_WHHH3 = OFF_WHHH2 + NWHH*2;
constexpr size_t OFF_WHHL0 = OFF_WHHH3 + NWHH3*2;
constexpr size_t OFF_WHHL1 = OFF_WHHL0 + NWHH*2;
constexpr size_t OFF_WHHL2 = OFF_WHHL1 + NWHH*2;
constexpr size_t OFF_WHHL3 = OFF_WHHL2 + NWHH*2;
constexpr size_t OFF_CENH  = OFF_WHHL3 + NWHH3*2;   // [2 parities]
constexpr size_t OFF_CENL  = OFF_CENH + 2*NCEN*2;
constexpr size_t OFF_CTXH  = OFF_CENL + 2*NCEN*2;
constexpr size_t OFF_CTXL  = OFF_CTXH + NCTX*2;
constexpr size_t OFF_HH    = OFF_CTXL + NCTX*2;     // [(p*4+i)]
constexpr size_t OFF_HL    = OFF_HH + 8*NHMX*2;
constexpr size_t OFF_HF    = OFF_HL + 8*NHMX*2;     // fp32
constexpr size_t WS_NEED   = OFF_HF + 8*NHMX*4;     // ~116 MB

__device__ __forceinline__ f16* hh_ptr(char* ws,int p,int i){ return (f16*)(ws+OFF_HH+((size_t)(p*4+i))*NHMX*2); }
__device__ __forceinline__ f16* hl_ptr(char* ws,int p,int i){ return (f16*)(ws+OFF_HL+((size_t)(p*4+i))*NHMX*2); }
__device__ __forceinline__ float* hf_ptr(char* ws,int p,int i){ return (float*)(ws+OFF_HF+((size_t)(p*4+i))*NHMX*4); }

// ---------------- prep: repack to fragment-major ----------------
__global__ void k_repack_w(const float* __restrict__ src, f16* __restrict__ hi,
                           f16* __restrict__ lo, int K){
    int n = blockIdx.x;
    const float* row = src + (size_t)n*K;
    int Kc = K >> 5;
    for (int k8 = threadIdx.x*8; k8 < K; k8 += 2048) {
        f16x8 hv, lv;
        #pragma unroll
        for (int e = 0; e < 8; ++e) { f16 a,b; fsplit(row[k8+e], &a, &b); hv[e]=a; lv[e]=b; }
        size_t d = fragoff(n, k8, Kc);
        *reinterpret_cast<f16x8*>(hi + d) = hv;
        *reinterpret_cast<f16x8*>(lo + d) = lv;
    }
}

__global__ void k_repack_pm(const float* __restrict__ p0, const float* __restrict__ p1,
                            const float* __restrict__ p2, const float* __restrict__ p3,
                            f16* __restrict__ hi, f16* __restrict__ lo){
    int k0 = blockIdx.x * 8;
    for (int c = threadIdx.x; c < 1024; c += 256) {
        int i = c >> 8, nl = c & 255;
        const float* p = (i==0?p0 : i==1?p1 : i==2?p2 : p3);
        #pragma unroll
        for (int e = 0; e < 8; ++e) {
            f16 a,b; fsplit(p[(size_t)(k0+e)*256 + nl], &a, &b);
            size_t d = fragoff(c, k0+e, 128); hi[d]=a; lo[d]=b;
        }
    }
}

__global__ void k_repack_x(const float* __restrict__ src, f16* __restrict__ hi, f16* __restrict__ lo){
    size_t g = ((size_t)blockIdx.x*256 + threadIdx.x) * 8;
    if (g >= NXE) return;
    int m = (int)(g >> 15), t = (int)((g >> 7) & 255), d0 = (int)(g & 127);
    f16x8 hv, lv;
    #pragma unroll
    for (int e = 0; e < 8; ++e) { f16 a,b; fsplit(src[g+e], &a, &b); hv[e]=a; lv[e]=b; }
    size_t d = (size_t)t*16384 + fragoff(m, d0, 4);
    *reinterpret_cast<f16x8*>(hi + d) = hv;
    *reinterpret_cast<f16x8*>(lo + d) = lv;
}

__global__ void k_init_cen(const float* __restrict__ ci, char* ws){
    size_t g = ((size_t)blockIdx.x*256 + threadIdx.x) * 8;
    if (g >= 4ull*128*1024) return;
    int i = (int)(g >> 17), b = (int)((g >> 10) & 127), c = (int)(g & 1023);
    f16* hi = (f16*)(ws + OFF_CENH);
    f16* lo = (f16*)(ws + OFF_CENL);
    f16x8 hv, lv;
    #pragma unroll
    for (int e = 0; e < 8; ++e) { f16 a,bb; fsplit(ci[g+e], &a, &bb); hv[e]=a; lv[e]=bb; }
    size_t d = fragoff(b, i*1024 + c, 128);
    *reinterpret_cast<f16x8*>(hi + d) = hv;
    *reinterpret_cast<f16x8*>(lo + d) = lv;
}

__global__ void k_init_mod(const float* __restrict__ mi, char* ws){
    size_t g = ((size_t)blockIdx.x*256 + threadIdx.x) * 8;
    if (g >= 3ull*128*1024) return;
    int i = (int)(g >> 17), b = (int)((g >> 10) & 127), j = (int)(g & 1023);
    float* hf = hf_ptr(ws, 0, i);
    f16 *hh = hh_ptr(ws, 0, i), *hl = hl_ptr(ws, 0, i);
    f16x8 hv, lv;
    #pragma unroll
    for (int e = 0; e < 8; ++e) {
        float v = mi[g+e]; hf[(size_t)b*1024 + j + e] = v;
        f16 a,bb; fsplit(v, &a, &bb); hv[e]=a; lv[e]=bb;
    }
    size_t d = fragoff(b, j, 32);
    *reinterpret_cast<f16x8*>(hh + d) = hv;
    *reinterpret_cast<f16x8*>(hl + d) = lv;
}

__global__ void k_init_last(const float* __restrict__ ml, char* ws){
    int b = blockIdx.x;
    float* hf = hf_ptr(ws, 0, 3);
    f16 *hh = hh_ptr(ws, 0, 3), *hl = hl_ptr(ws, 0, 3);
    for (int j = threadIdx.x*8; j < 1152; j += 2048) {
        f16x8 hv, lv;
        #pragma unroll
        for (int e = 0; e < 8; ++e) {
            float v = ml[(size_t)b*1152 + j + e]; hf[(size_t)b*1152 + j + e] = v;
            f16 a,bb; fsplit(v, &a, &bb); hv[e]=a; lv[e]=bb;
        }
        size_t d = fragoff(b, j, 36);
        *reinterpret_cast<f16x8*>(hh + d) = hv;
        *reinterpret_cast<f16x8*>(hl + d) = lv;
    }
}

// ---------------- step kernel 1: ctx = center @ pm (unchanged from R4) ----------------
// 256 blocks x 512 thr: tile (32 rows x 16 cols), 8-wave K-split (512 each), LDS reduce.
__global__ __launch_bounds__(512) void k_ctx(char* ws, int par){
    __shared__ float red[8][32][17];
    const f16* cenh = (const f16*)(ws + OFF_CENH) + (size_t)par*NCEN;
    const f16* cenl = (const f16*)(ws + OFF_CENL) + (size_t)par*NCEN;
    const f16* pmh  = (const f16*)(ws + OFF_PMH);
    const f16* pml  = (const f16*)(ws + OFF_PML);
    int tid = threadIdx.x, lane = tid & 63, wv = tid >> 6;
    int bm = blockIdx.x >> 6, bn = blockIdx.x & 63;
    size_t lb = (size_t)lane*8;
    size_t a0 = ((size_t)(bm*2)*128 + wv*16)*512 + lb;
    size_t a1 = a0 + 128*512;
    size_t bb = ((size_t)bn*128 + wv*16)*512 + lb;
    f32x4 h0={},h1={},c0={},c1={};
    #pragma unroll 4
    for (int kc = 0; kc < 16; ++kc) {
        f16x8 bh = ld8h(pmh + bb + kc*512), bl = ld8h(pml + bb + kc*512);
        f16x8 ah0 = ld8h(cenh + a0 + kc*512), al0 = ld8h(cenl + a0 + kc*512);
        f16x8 ah1 = ld8h(cenh + a1 + kc*512), al1 = ld8h(cenl + a1 + kc*512);
        h0 = MFMA16(ah0,bh,h0); c0 = MFMA16(al0,bh,c0); c0 = MFMA16(ah0,bl,c0);
        h1 = MFMA16(ah1,bh,h1); c1 = MFMA16(al1,bh,c1); c1 = MFMA16(ah1,bl,c1);
    }
    int rg = lane >> 4, fr = lane & 15;
    const float inv = 1.0f/4096.0f;
    #pragma unroll
    for (int rr = 0; rr < 4; ++rr) {
        red[wv][rg*4+rr][fr]      = h0[rr] + c0[rr]*inv;
        red[wv][16+rg*4+rr][fr]   = h1[rr] + c1[rr]*inv;
    }
    __syncthreads();
    int r = tid >> 4, c = tid & 15;   // 512 threads = 32x16
    float s = red[0][r][c]+red[1][r][c]+red[2][r][c]+red[3][r][c]
            + red[4][r][c]+red[5][r][c]+red[6][r][c]+red[7][r][c];
    int m = bm*32 + r, n = bn*16 + c;
    size_t d = fragoff(m, n, 32);
    f16* ctxh = (f16*)(ws + OFF_CTXH);
    f16* ctxl = (f16*)(ws + OFF_CTXL);
    fsplit(s, &ctxh[d], &ctxl[d]);
}

// ---------------- step kernel 2: fused gates+GRU, 8 waves/block (2 waves/SIMD) ----------------
// 264 blocks x 512 thr: block = (module i, 16 h-cols) x 128 rows; wave = 1 m-frag (16 rows).
__global__ __launch_bounds__(512, 2) void k_fused(char* ws,
    const float* __restrict__ bih0, const float* __restrict__ bih1,
    const float* __restrict__ bih2, const float* __restrict__ bih3,
    const float* __restrict__ bhh0, const float* __restrict__ bhh1,
    const float* __restrict__ bhh2, const float* __restrict__ bhh3,
    float* __restrict__ out, int t, int par)
{
    const int tid = threadIdx.x, lane = tid & 63, wv = tid >> 6;   // wv = m-frag 0..7
    const int fr = lane & 15, rg = lane >> 4;
    const int tile = blockIdx.x;
    int i, jt;
    if (tile < 64)       { i = 0; jt = tile; }
    else if (tile < 128) { i = 1; jt = tile - 64; }
    else if (tile < 192) { i = 2; jt = tile - 128; }
    else                 { i = 3; jt = tile - 192; }
    const int H  = (i == 3) ? 1152 : 1024;
    const int K1 = (i == 0) ? 384 : 256;
    const int Kc1 = K1 >> 5, KcH = H >> 5, Ht = H >> 4;

    const f16* WihH = (const f16*)(ws + (i==0?OFF_WIHH0 : i==1?OFF_WIHH1 : i==2?OFF_WIHH2 : OFF_WIHH3));
    const f16* WihL = (const f16*)(ws + (i==0?OFF_WIHL0 : i==1?OFF_WIHL1 : i==2?OFF_WIHL2 : OFF_WIHL3));
    const f16* WhhH = (const f16*)(ws + (i==0?OFF_WHHH0 : i==1?OFF_WHHH1 : i==2?OFF_WHHH2 : OFF_WHHH3));
    const f16* WhhL = (const f16*)(ws + (i==0?OFF_WHHL0 : i==1?OFF_WHHL1 : i==2?OFF_WHHL2 : OFF_WHHL3));

    const size_t lb = (size_t)lane*8;
    size_t b1[3], b2[3];
    #pragma unroll
    for (int s = 0; s < 3; ++s) {
        b1[s] = ((size_t)(s*Ht + jt)*Kc1)*512 + lb;
        b2[s] = ((size_t)(s*Ht + jt)*KcH)*512 + lb;
    }
    const int mf = wv;   // one 16-row m-frag per wave

    f32x4 rh={},rc={},zh={},zc={},inh={},inc={},nhh={},nhc={};

    // ---- ih GEMM: A = (i==0 ? [x_t | ctx0] : ctx_i) ----
    {
        const f16* XH_ = (const f16*)(ws + OFF_XH);
        const f16* XL_ = (const f16*)(ws + OFF_XL);
        const f16* CH_ = (const f16*)(ws + OFF_CTXH);
        const f16* CL_ = (const f16*)(ws + OFF_CTXL);
        size_t xb = ((size_t)(t*8 + mf)*4)*512 + lb;
        size_t cb = ((size_t)mf*32)*512 + lb;
        #pragma unroll 4
        for (int kc = 0; kc < Kc1; ++kc) {
            f16x8 ah, al;
            if (i == 0 && kc < 4) { ah = ld8h(XH_ + xb + kc*512); al = ld8h(XL_ + xb + kc*512); }
            else { int ck = (i == 0) ? kc - 4 : i*8 + kc;
                   ah = ld8h(CH_ + cb + ck*512); al = ld8h(CL_ + cb + ck*512); }
            f16x8 bh, bl;
            bh = ld8h(WihH + b1[0] + kc*512); bl = ld8h(WihL + b1[0] + kc*512);
            rh = MFMA16(ah,bh,rh); rc = MFMA16(al,bh,rc); rc = MFMA16(ah,bl,rc);
            bh = ld8h(WihH + b1[1] + kc*512); bl = ld8h(WihL + b1[1] + kc*512);
            zh = MFMA16(ah,bh,zh); zc = MFMA16(al,bh,zc); zc = MFMA16(ah,bl,zc);
            bh = ld8h(WihH + b1[2] + kc*512); bl = ld8h(WihL + b1[2] + kc*512);
            inh = MFMA16(ah,bh,inh); inc = MFMA16(al,bh,inc); inc = MFMA16(ah,bl,inc);
        }
    }
    // ---- hh GEMM: A = h_prev (parity par) ----
    {
        const f16* HHp = hh_ptr(ws, par, i);
        const f16* HLp = hl_ptr(ws, par, i);
        size_t hb = ((size_t)mf*KcH)*512 + lb;
        #pragma unroll 4
        for (int kc = 0; kc < KcH; ++kc) {
            f16x8 ah = ld8h(HHp + hb + kc*512), al = ld8h(HLp + hb + kc*512);
            f16x8 bh, bl;
            bh = ld8h(WhhH + b2[0] + kc*512); bl = ld8h(WhhL + b2[0] + kc*512);
            rh = MFMA16(ah,bh,rh); rc = MFMA16(al,bh,rc); rc = MFMA16(ah,bl,rc);
            bh = ld8h(WhhH + b2[1] + kc*512); bl = ld8h(WhhL + b2[1] + kc*512);
            zh = MFMA16(ah,bh,zh); zc = MFMA16(al,bh,zc); zc = MFMA16(ah,bl,zc);
            bh = ld8h(WhhH + b2[2] + kc*512); bl = ld8h(WhhL + b2[2] + kc*512);
            nhh = MFMA16(ah,bh,nhh); nhc = MFMA16(al,bh,nhc); nhc = MFMA16(ah,bl,nhc);
        }
    }

    // ---- GRU epilogue ----
    const float* bihp = (i==0?bih0 : i==1?bih1 : i==2?bih2 : bih3);
    const float* bhhp = (i==0?bhh0 : i==1?bhh1 : i==2?bhh2 : bhh3);
    const int j = jt*16 + fr;
    const float bir = bihp[j], biz = bihp[H+j], bin = bihp[2*H+j];
    const float bhr = bhhp[j], bhz = bhhp[H+j], bhn = bhhp[2*H+j];
    const float* hfP = hf_ptr(ws, par, i);
    float* hfN = hf_ptr(ws, par^1, i);
    f16 *hhN = hh_ptr(ws, par^1, i), *hlN = hl_ptr(ws, par^1, i);
    f16* cenhN = (f16*)(ws + OFF_CENH) + (size_t)(par^1)*NCEN;
    f16* cenlN = (f16*)(ws + OFF_CENL) + (size_t)(par^1)*NCEN;
    const float inv = 1.0f/4096.0f;
    #pragma unroll
    for (int rr = 0; rr < 4; ++rr) {
        float r_  = rh[rr]  + rc[rr]*inv  + bir + bhr;
        float z_  = zh[rr]  + zc[rr]*inv  + biz + bhz;
        float in_ = inh[rr] + inc[rr]*inv + bin;
        float hn_ = nhh[rr] + nhc[rr]*inv + bhn;
        float rgt = 1.f/(1.f + expf(-r_));
        float zgt = 1.f/(1.f + expf(-z_));
        float ngt = tanhf(in_ + rgt*hn_);
        int m = mf*16 + rg*4 + rr;
        float hp = hfP[(size_t)m*H + j];
        float hnew = (1.f - zgt)*ngt + zgt*hp;
        hfN[(size_t)m*H + j] = hnew;
        size_t hd = fragoff(m, j, KcH);
        fsplit(hnew, &hhN[hd], &hlN[hd]);
        if (i < 3) {
            size_t cd = fragoff(m, i*1024 + j, 128);
            fsplit(hnew, &cenhN[cd], &cenlN[cd]);
        } else if (j >= 128) {
            size_t cd = fragoff(m, 3072 + j - 128, 128);
            fsplit(hnew, &cenhN[cd], &cenlN[cd]);
        } else {
            out[((size_t)m*256 + t)*128 + j] = hnew;
        }
    }
}

// ---------------- host ----------------
extern "C" void kernel_launch(void* const* d_in, const int* in_sizes, int n_in,
                              void* d_out, int out_size, void* d_ws, size_t ws_size,
                              hipStream_t stream)
{
    char* ws = (char*)d_ws;
    const float* inp   = (const float*)d_in[0];
    const float* cini  = (const float*)d_in[1];
    const float* mini  = (const float*)d_in[2];
    const float* mlast = (const float*)d_in[3];
    const float *pm[4], *wih[4], *whh[4], *bih[4], *bhh[4];
    for (int i = 0; i < 4; ++i) {
        pm[i]  = (const float*)d_in[4 + 5*i];
        wih[i] = (const float*)d_in[5 + 5*i];
        whh[i] = (const float*)d_in[6 + 5*i];
        bih[i] = (const float*)d_in[7 + 5*i];
        bhh[i] = (const float*)d_in[8 + 5*i];
    }
    float* out = (float*)d_out;

    k_repack_x<<<2048, 256, 0, stream>>>(inp, (f16*)(ws+OFF_XH), (f16*)(ws+OFF_XL));
    k_repack_pm<<<512, 256, 0, stream>>>(pm[0], pm[1], pm[2], pm[3],
                                         (f16*)(ws+OFF_PMH), (f16*)(ws+OFF_PML));
    k_repack_w<<<3072, 256, 0, stream>>>(wih[0], (f16*)(ws+OFF_WIHH0), (f16*)(ws+OFF_WIHL0), 384);
    k_repack_w<<<3072, 256, 0, stream>>>(wih[1], (f16*)(ws+OFF_WIHH1), (f16*)(ws+OFF_WIHL1), 256);
    k_repack_w<<<3072, 256, 0, stream>>>(wih[2], (f16*)(ws+OFF_WIHH2), (f16*)(ws+OFF_WIHL2), 256);
    k_repack_w<<<3456, 256, 0, stream>>>(wih[3], (f16*)(ws+OFF_WIHH3), (f16*)(ws+OFF_WIHL3), 256);
    k_repack_w<<<3072, 256, 0, stream>>>(whh[0], (f16*)(ws+OFF_WHHH0), (f16*)(ws+OFF_WHHL0), 1024);
    k_repack_w<<<3072, 256, 0, stream>>>(whh[1], (f16*)(ws+OFF_WHHH1), (f16*)(ws+OFF_WHHL1), 1024);
    k_repack_w<<<3072, 256, 0, stream>>>(whh[2], (f16*)(ws+OFF_WHHH2), (f16*)(ws+OFF_WHHL2), 1024);
    k_repack_w<<<3456, 256, 0, stream>>>(whh[3], (f16*)(ws+OFF_WHHH3), (f16*)(ws+OFF_WHHL3), 1152);
    k_init_cen<<<256, 256, 0, stream>>>(cini, ws);
    k_init_mod<<<192, 256, 0, stream>>>(mini, ws);
    k_init_last<<<128, 256, 0, stream>>>(mlast, ws);

    for (int t = 0; t < 256; ++t) {
        int par = t & 1;
        k_ctx<<<256, 512, 0, stream>>>(ws, par);
        k_fused<<<264, 512, 0, stream>>>(ws,
            bih[0], bih[1], bih[2], bih[3],
            bhh[0], bhh[1], bhh[2], bhh[3],
            out, t, par);
    }
    (void)in_sizes; (void)n_in; (void)out_size; (void)ws_size; (void)WS_NEED;
}